// Round 9
// baseline (69.321 us; speedup 1.0000x reference)
//
#include <hip/hip_runtime.h>

#define BB 8
#define SS 4096
#define NN 1024
#define DD 1024
#define NUM_WIDTH 64
#define WIDTH_DIM 64
#define OUTD (DD + WIDTH_DIM)   // 1088
#define NSPAN (BB * NN)         // 8192
#define NBUCK 128               // per-batch start buckets (start >> 5)
#define NBINS (BB * NBUCK)      // 1024

// ---- fused counting sort; emits sorted metadata records (bn,start,end) ----
__global__ __launch_bounds__(1024) void sort_kernel(const int2* __restrict__ idx2,
                                                    int4* __restrict__ meta) {
    __shared__ int cnt[NBINS];
    __shared__ int wsum[16];
    int tid = threadIdx.x, lane = tid & 63, wid = tid >> 6;
    cnt[tid] = 0;
    __syncthreads();

    for (int i = tid; i < NSPAN; i += 1024) {
        int2 se = idx2[i];
        int s0 = se.x > 0 ? se.x : 0;
        if (s0 > SS - 1) s0 = SS - 1;
        atomicAdd(&cnt[(i >> 10) * NBUCK + (s0 >> 5)], 1);
    }
    __syncthreads();

    // wave-level inclusive scan of the 1024 bin counts
    int orig = cnt[tid];
    int x = orig;
    #pragma unroll
    for (int d = 1; d < 64; d <<= 1) {
        int y = __shfl_up(x, d, 64);
        if (lane >= d) x += y;
    }
    if (lane == 63) wsum[wid] = x;
    __syncthreads();
    if (wid == 0) {
        int s = (lane < 16) ? wsum[lane] : 0;
        #pragma unroll
        for (int d = 1; d < 16; d <<= 1) {
            int y = __shfl_up(s, d, 64);
            if (lane >= d) s += y;
        }
        if (lane < 16) wsum[lane] = s;
    }
    __syncthreads();
    int excl = x - orig + (wid > 0 ? wsum[wid - 1] : 0);
    __syncthreads();
    cnt[tid] = excl;
    __syncthreads();

    for (int i = tid; i < NSPAN; i += 1024) {
        int2 se = idx2[i];
        int s0 = se.x > 0 ? se.x : 0;
        if (s0 > SS - 1) s0 = SS - 1;
        int pos = atomicAdd(&cnt[(i >> 10) * NBUCK + (s0 >> 5)], 1);
        meta[pos] = make_int4(i, se.x, se.y, 0);
    }
}

// ---- span kernel: 8 waves/span, single batch, no online rescale ----
__global__ __launch_bounds__(512, 4) void span_kernel(const float* __restrict__ seq,
                                                      const float* __restrict__ w,
                                                      const float* __restrict__ wemb,
                                                      const int4* __restrict__ meta,
                                                      float* __restrict__ out) {
    // XCD-chunked swizzle over the sorted span order -> per-XCD L2 locality.
    int swz = (blockIdx.x & 7) * (NSPAN / 8) + (blockIdx.x >> 3);
    int4 me = meta[swz];
    int bn = me.x, start = me.y, end = me.z;
    int b  = bn >> 10;
    int tid = threadIdx.x;
    int wave = tid >> 6;
    int lane = tid & 63;

    int s0 = start > 0 ? start : 0;
    int eC = end < (SS - 1) ? end : (SS - 1);
    int L  = (start >= 0 && end >= start) ? (eC - s0 + 1) : 0;
    if (L < 0) L = 0;
    if (L > 32) L = 32;

    // width embedding early: independent store, overlaps the gather
    if (tid < WIDTH_DIM) {
        int wdt = end - start;
        if (wdt < 0) wdt = 0;
        if (wdt > NUM_WIDTH - 1) wdt = NUM_WIDTH - 1;
        out[(long long)bn * OUTD + DD + tid] = wemb[wdt * WIDTH_DIM + tid];
    }

    __shared__ float lds_acc[8][DD];     // 32 KB: per-wave unscaled partials
    __shared__ float lds_wm[8];          // per-wave max
    __shared__ float lds_wz[8];          // per-wave Z (post-mg)

    const float4* s4 = (const float4*)(seq + ((long long)b * SS + s0) * DD);
    const float4* w4 = (const float4*)w;
    float4 wr0 = w4[lane], wr1 = w4[64 + lane], wr2 = w4[128 + lane], wr3 = w4[192 + lane];

    // each wave owns rows {wave, wave+8, wave+16, wave+24} ∩ [0,L)
    int lm1 = (L > 0) ? (L - 1) : 0;
    bool v0 = (wave      ) < L;  int rc0 = v0 ? (wave     ) : lm1;
    bool v1 = (wave +  8 ) < L;  int rc1 = v1 ? (wave +  8) : lm1;
    bool v2 = (wave + 16 ) < L;  int rc2 = v2 ? (wave + 16) : lm1;
    bool v3 = (wave + 24 ) < L;  int rc3 = v3 ? (wave + 24) : lm1;

    const float4* p0 = s4 + (long long)rc0 * (DD / 4);
    const float4* p1 = s4 + (long long)rc1 * (DD / 4);
    const float4* p2 = s4 + (long long)rc2 * (DD / 4);
    const float4* p3 = s4 + (long long)rc3 * (DD / 4);

    // 16 independent 16B loads, all in flight at once
    float4 a00 = p0[lane], a01 = p0[64 + lane], a02 = p0[128 + lane], a03 = p0[192 + lane];
    float4 a10 = p1[lane], a11 = p1[64 + lane], a12 = p1[128 + lane], a13 = p1[192 + lane];
    float4 a20 = p2[lane], a21 = p2[64 + lane], a22 = p2[128 + lane], a23 = p2[192 + lane];
    float4 a30 = p3[lane], a31 = p3[64 + lane], a32 = p3[128 + lane], a33 = p3[192 + lane];

    float d0 = a00.x * wr0.x + a00.y * wr0.y + a00.z * wr0.z + a00.w * wr0.w
             + a01.x * wr1.x + a01.y * wr1.y + a01.z * wr1.z + a01.w * wr1.w
             + a02.x * wr2.x + a02.y * wr2.y + a02.z * wr2.z + a02.w * wr2.w
             + a03.x * wr3.x + a03.y * wr3.y + a03.z * wr3.z + a03.w * wr3.w;
    float d1 = a10.x * wr0.x + a10.y * wr0.y + a10.z * wr0.z + a10.w * wr0.w
             + a11.x * wr1.x + a11.y * wr1.y + a11.z * wr1.z + a11.w * wr1.w
             + a12.x * wr2.x + a12.y * wr2.y + a12.z * wr2.z + a12.w * wr2.w
             + a13.x * wr3.x + a13.y * wr3.y + a13.z * wr3.z + a13.w * wr3.w;
    float d2 = a20.x * wr0.x + a20.y * wr0.y + a20.z * wr0.z + a20.w * wr0.w
             + a21.x * wr1.x + a21.y * wr1.y + a21.z * wr1.z + a21.w * wr1.w
             + a22.x * wr2.x + a22.y * wr2.y + a22.z * wr2.z + a22.w * wr2.w
             + a23.x * wr3.x + a23.y * wr3.y + a23.z * wr3.z + a23.w * wr3.w;
    float d3 = a30.x * wr0.x + a30.y * wr0.y + a30.z * wr0.z + a30.w * wr0.w
             + a31.x * wr1.x + a31.y * wr1.y + a31.z * wr1.z + a31.w * wr1.w
             + a32.x * wr2.x + a32.y * wr2.y + a32.z * wr2.z + a32.w * wr2.w
             + a33.x * wr3.x + a33.y * wr3.y + a33.z * wr3.z + a33.w * wr3.w;

    // 4 interleaved butterfly reduces (chains overlap)
    #pragma unroll
    for (int s = 32; s >= 1; s >>= 1) {
        d0 += __shfl_xor(d0, s, 64);
        d1 += __shfl_xor(d1, s, 64);
        d2 += __shfl_xor(d2, s, 64);
        d3 += __shfl_xor(d3, s, 64);
    }

    // per-wave max of its valid dots
    float mw = -INFINITY;
    if (v0) mw = fmaxf(mw, d0);
    if (v1) mw = fmaxf(mw, d1);
    if (v2) mw = fmaxf(mw, d2);
    if (v3) mw = fmaxf(mw, d3);
    if (lane == 0) lds_wm[wave] = mw;
    __syncthreads();

    // global max (8 independent LDS reads, broadcast)
    float mg = fmaxf(fmaxf(fmaxf(lds_wm[0], lds_wm[1]), fmaxf(lds_wm[2], lds_wm[3])),
                     fmaxf(fmaxf(lds_wm[4], lds_wm[5]), fmaxf(lds_wm[6], lds_wm[7])));

    float x0 = v0 ? __expf(d0 - mg) : 0.f;
    float x1 = v1 ? __expf(d1 - mg) : 0.f;
    float x2 = v2 ? __expf(d2 - mg) : 0.f;
    float x3 = v3 ? __expf(d3 - mg) : 0.f;
    if (lane == 0) lds_wz[wave] = x0 + x1 + x2 + x3;

    // accumulate from registers (unscaled)
    float4 acc0, acc1, acc2, acc3;
    acc0.x = x0 * a00.x + x1 * a10.x + x2 * a20.x + x3 * a30.x;
    acc0.y = x0 * a00.y + x1 * a10.y + x2 * a20.y + x3 * a30.y;
    acc0.z = x0 * a00.z + x1 * a10.z + x2 * a20.z + x3 * a30.z;
    acc0.w = x0 * a00.w + x1 * a10.w + x2 * a20.w + x3 * a30.w;
    acc1.x = x0 * a01.x + x1 * a11.x + x2 * a21.x + x3 * a31.x;
    acc1.y = x0 * a01.y + x1 * a11.y + x2 * a21.y + x3 * a31.y;
    acc1.z = x0 * a01.z + x1 * a11.z + x2 * a21.z + x3 * a31.z;
    acc1.w = x0 * a01.w + x1 * a11.w + x2 * a21.w + x3 * a31.w;
    acc2.x = x0 * a02.x + x1 * a12.x + x2 * a22.x + x3 * a32.x;
    acc2.y = x0 * a02.y + x1 * a12.y + x2 * a22.y + x3 * a32.y;
    acc2.z = x0 * a02.z + x1 * a12.z + x2 * a22.z + x3 * a32.z;
    acc2.w = x0 * a02.w + x1 * a12.w + x2 * a22.w + x3 * a32.w;
    acc3.x = x0 * a03.x + x1 * a13.x + x2 * a23.x + x3 * a33.x;
    acc3.y = x0 * a03.y + x1 * a13.y + x2 * a23.y + x3 * a33.y;
    acc3.z = x0 * a03.z + x1 * a13.z + x2 * a23.z + x3 * a33.z;
    acc3.w = x0 * a03.w + x1 * a13.w + x2 * a23.w + x3 * a33.w;

    float4* la = (float4*)lds_acc[wave];
    la[lane] = acc0; la[64 + lane] = acc1; la[128 + lane] = acc2; la[192 + lane] = acc3;
    __syncthreads();

    float Zg = lds_wz[0] + lds_wz[1] + lds_wz[2] + lds_wz[3]
             + lds_wz[4] + lds_wz[5] + lds_wz[6] + lds_wz[7];
    float inv = (Zg > 0.f) ? 1.0f / Zg : 0.f;

    // 8-way combine: thread t owns columns 2t, 2t+1
    float sx = 0.f, sy = 0.f;
    #pragma unroll
    for (int wv = 0; wv < 8; ++wv) {
        float2 v = *(const float2*)&lds_acc[wv][2 * tid];
        sx += v.x; sy += v.y;
    }
    float2 o = make_float2(sx * inv, sy * inv);
    *(float2*)&out[(long long)bn * OUTD + 2 * tid] = o;
}

extern "C" void kernel_launch(void* const* d_in, const int* in_sizes, int n_in,
                              void* d_out, int out_size, void* d_ws, size_t ws_size,
                              hipStream_t stream) {
    const float* seq  = (const float*)d_in[0];
    const int*   idx  = (const int*)d_in[1];
    const float* w    = (const float*)d_in[2];
    const float* wemb = (const float*)d_in[4];
    float* out = (float*)d_out;

    int4* meta = (int4*)d_ws;            // NSPAN * 16 B = 128 KB

    sort_kernel<<<1, 1024, 0, stream>>>((const int2*)idx, meta);
    span_kernel<<<NSPAN, 512, 0, stream>>>(seq, w, wemb, meta, out);
}

// Round 10
// 64.683 us; speedup vs baseline: 1.0717x; 1.0717x over previous
//
#include <hip/hip_runtime.h>

#define BB 8
#define SS 4096
#define NN 1024
#define DD 1024
#define NUM_WIDTH 64
#define WIDTH_DIM 64
#define OUTD (DD + WIDTH_DIM)   // 1088
#define NSPAN (BB * NN)         // 8192
#define NBUCK 128               // per-batch start buckets (start >> 5)
#define NBINS (BB * NBUCK)      // 1024

// ---- fused counting sort; emits sorted metadata records (bn,start,end) ----
__global__ __launch_bounds__(1024) void sort_kernel(const int2* __restrict__ idx2,
                                                    int4* __restrict__ meta) {
    __shared__ int cnt[NBINS];
    __shared__ int wsum[16];
    int tid = threadIdx.x, lane = tid & 63, wid = tid >> 6;
    cnt[tid] = 0;
    __syncthreads();

    for (int i = tid; i < NSPAN; i += 1024) {
        int2 se = idx2[i];
        int s0 = se.x > 0 ? se.x : 0;
        if (s0 > SS - 1) s0 = SS - 1;
        atomicAdd(&cnt[(i >> 10) * NBUCK + (s0 >> 5)], 1);
    }
    __syncthreads();

    // wave-level inclusive scan of the 1024 bin counts
    int orig = cnt[tid];
    int x = orig;
    #pragma unroll
    for (int d = 1; d < 64; d <<= 1) {
        int y = __shfl_up(x, d, 64);
        if (lane >= d) x += y;
    }
    if (lane == 63) wsum[wid] = x;
    __syncthreads();
    if (wid == 0) {
        int s = (lane < 16) ? wsum[lane] : 0;
        #pragma unroll
        for (int d = 1; d < 16; d <<= 1) {
            int y = __shfl_up(s, d, 64);
            if (lane >= d) s += y;
        }
        if (lane < 16) wsum[lane] = s;
    }
    __syncthreads();
    int excl = x - orig + (wid > 0 ? wsum[wid - 1] : 0);
    __syncthreads();
    cnt[tid] = excl;
    __syncthreads();

    for (int i = tid; i < NSPAN; i += 1024) {
        int2 se = idx2[i];
        int s0 = se.x > 0 ? se.x : 0;
        if (s0 > SS - 1) s0 = SS - 1;
        int pos = atomicAdd(&cnt[(i >> 10) * NBUCK + (s0 >> 5)], 1);
        meta[pos] = make_int4(i, se.x, se.y, 0);
    }
}

// ---- span kernel: 8 waves/span, single batch, wave-uniform predicated ----
__global__ __launch_bounds__(512, 4) void span_kernel(const float* __restrict__ seq,
                                                      const float* __restrict__ w,
                                                      const float* __restrict__ wemb,
                                                      const int4* __restrict__ meta,
                                                      float* __restrict__ out) {
    // XCD-chunked swizzle over the sorted span order -> per-XCD L2 locality.
    int swz = (blockIdx.x & 7) * (NSPAN / 8) + (blockIdx.x >> 3);
    int4 me = meta[swz];
    int bn = me.x, start = me.y, end = me.z;
    int b  = bn >> 10;
    int tid = threadIdx.x;
    int wave = tid >> 6;
    int lane = tid & 63;

    int s0 = start > 0 ? start : 0;
    int eC = end < (SS - 1) ? end : (SS - 1);
    int L  = (start >= 0 && end >= start) ? (eC - s0 + 1) : 0;
    if (L < 0) L = 0;
    if (L > 32) L = 32;

    // width embedding early: independent store, overlaps the gather
    if (tid < WIDTH_DIM) {
        int wdt = end - start;
        if (wdt < 0) wdt = 0;
        if (wdt > NUM_WIDTH - 1) wdt = NUM_WIDTH - 1;
        out[(long long)bn * OUTD + DD + tid] = wemb[wdt * WIDTH_DIM + tid];
    }

    __shared__ float lds_acc[8][DD];     // 32 KB: per-wave unscaled partials
    __shared__ float lds_wm[8];          // per-wave max
    __shared__ float lds_wz[8];          // per-wave Z (post-mg)

    const float4* s4 = (const float4*)(seq + ((long long)b * SS + s0) * DD);
    const float4* w4 = (const float4*)w;
    float4 wr0 = w4[lane], wr1 = w4[64 + lane], wr2 = w4[128 + lane], wr3 = w4[192 + lane];

    // each wave owns rows {wave, wave+8, wave+16, wave+24} ∩ [0,L)
    bool v0 = (wave      ) < L;
    bool v1 = (wave +  8 ) < L;
    bool v2 = (wave + 16 ) < L;
    bool v3 = (wave + 24 ) < L;

    float4 zz = make_float4(0.f, 0.f, 0.f, 0.f);
    float4 a00 = zz, a01 = zz, a02 = zz, a03 = zz;
    float4 a10 = zz, a11 = zz, a12 = zz, a13 = zz;
    float4 a20 = zz, a21 = zz, a22 = zz, a23 = zz;
    float4 a30 = zz, a31 = zz, a32 = zz, a33 = zz;

    // wave-uniform branches (v* depend only on wave,L): scalar branch, no
    // divergence; loads for valid slots all issue before first use.
    if (v0) {
        const float4* p = s4 + (long long)(wave     ) * (DD / 4);
        a00 = p[lane]; a01 = p[64 + lane]; a02 = p[128 + lane]; a03 = p[192 + lane];
    }
    if (v1) {
        const float4* p = s4 + (long long)(wave +  8) * (DD / 4);
        a10 = p[lane]; a11 = p[64 + lane]; a12 = p[128 + lane]; a13 = p[192 + lane];
    }
    if (v2) {
        const float4* p = s4 + (long long)(wave + 16) * (DD / 4);
        a20 = p[lane]; a21 = p[64 + lane]; a22 = p[128 + lane]; a23 = p[192 + lane];
    }
    if (v3) {
        const float4* p = s4 + (long long)(wave + 24) * (DD / 4);
        a30 = p[lane]; a31 = p[64 + lane]; a32 = p[128 + lane]; a33 = p[192 + lane];
    }

    float d0 = a00.x * wr0.x + a00.y * wr0.y + a00.z * wr0.z + a00.w * wr0.w
             + a01.x * wr1.x + a01.y * wr1.y + a01.z * wr1.z + a01.w * wr1.w
             + a02.x * wr2.x + a02.y * wr2.y + a02.z * wr2.z + a02.w * wr2.w
             + a03.x * wr3.x + a03.y * wr3.y + a03.z * wr3.z + a03.w * wr3.w;
    float d1 = a10.x * wr0.x + a10.y * wr0.y + a10.z * wr0.z + a10.w * wr0.w
             + a11.x * wr1.x + a11.y * wr1.y + a11.z * wr1.z + a11.w * wr1.w
             + a12.x * wr2.x + a12.y * wr2.y + a12.z * wr2.z + a12.w * wr2.w
             + a13.x * wr3.x + a13.y * wr3.y + a13.z * wr3.z + a13.w * wr3.w;
    float d2 = a20.x * wr0.x + a20.y * wr0.y + a20.z * wr0.z + a20.w * wr0.w
             + a21.x * wr1.x + a21.y * wr1.y + a21.z * wr1.z + a21.w * wr1.w
             + a22.x * wr2.x + a22.y * wr2.y + a22.z * wr2.z + a22.w * wr2.w
             + a23.x * wr3.x + a23.y * wr3.y + a23.z * wr3.z + a23.w * wr3.w;
    float d3 = a30.x * wr0.x + a30.y * wr0.y + a30.z * wr0.z + a30.w * wr0.w
             + a31.x * wr1.x + a31.y * wr1.y + a31.z * wr1.z + a31.w * wr1.w
             + a32.x * wr2.x + a32.y * wr2.y + a32.z * wr2.z + a32.w * wr2.w
             + a33.x * wr3.x + a33.y * wr3.y + a33.z * wr3.z + a33.w * wr3.w;

    // 4 interleaved butterfly reduces (chains overlap)
    #pragma unroll
    for (int s = 32; s >= 1; s >>= 1) {
        d0 += __shfl_xor(d0, s, 64);
        d1 += __shfl_xor(d1, s, 64);
        d2 += __shfl_xor(d2, s, 64);
        d3 += __shfl_xor(d3, s, 64);
    }

    // per-wave max of its valid dots
    float mw = -INFINITY;
    if (v0) mw = fmaxf(mw, d0);
    if (v1) mw = fmaxf(mw, d1);
    if (v2) mw = fmaxf(mw, d2);
    if (v3) mw = fmaxf(mw, d3);
    if (lane == 0) lds_wm[wave] = mw;
    __syncthreads();

    // global max (8 independent LDS reads, broadcast)
    float mg = fmaxf(fmaxf(fmaxf(lds_wm[0], lds_wm[1]), fmaxf(lds_wm[2], lds_wm[3])),
                     fmaxf(fmaxf(lds_wm[4], lds_wm[5]), fmaxf(lds_wm[6], lds_wm[7])));

    float x0 = v0 ? __expf(d0 - mg) : 0.f;
    float x1 = v1 ? __expf(d1 - mg) : 0.f;
    float x2 = v2 ? __expf(d2 - mg) : 0.f;
    float x3 = v3 ? __expf(d3 - mg) : 0.f;
    if (lane == 0) lds_wz[wave] = x0 + x1 + x2 + x3;

    // accumulate from registers (unscaled); zeroed regs make invalid slots 0
    float4 acc0, acc1, acc2, acc3;
    acc0.x = x0 * a00.x + x1 * a10.x + x2 * a20.x + x3 * a30.x;
    acc0.y = x0 * a00.y + x1 * a10.y + x2 * a20.y + x3 * a30.y;
    acc0.z = x0 * a00.z + x1 * a10.z + x2 * a20.z + x3 * a30.z;
    acc0.w = x0 * a00.w + x1 * a10.w + x2 * a20.w + x3 * a30.w;
    acc1.x = x0 * a01.x + x1 * a11.x + x2 * a21.x + x3 * a31.x;
    acc1.y = x0 * a01.y + x1 * a11.y + x2 * a21.y + x3 * a31.y;
    acc1.z = x0 * a01.z + x1 * a11.z + x2 * a21.z + x3 * a31.z;
    acc1.w = x0 * a01.w + x1 * a11.w + x2 * a21.w + x3 * a31.w;
    acc2.x = x0 * a02.x + x1 * a12.x + x2 * a22.x + x3 * a32.x;
    acc2.y = x0 * a02.y + x1 * a12.y + x2 * a22.y + x3 * a32.y;
    acc2.z = x0 * a02.z + x1 * a12.z + x2 * a22.z + x3 * a32.z;
    acc2.w = x0 * a02.w + x1 * a12.w + x2 * a22.w + x3 * a32.w;
    acc3.x = x0 * a03.x + x1 * a13.x + x2 * a23.x + x3 * a33.x;
    acc3.y = x0 * a03.y + x1 * a13.y + x2 * a23.y + x3 * a33.y;
    acc3.z = x0 * a03.z + x1 * a13.z + x2 * a23.z + x3 * a33.z;
    acc3.w = x0 * a03.w + x1 * a13.w + x2 * a23.w + x3 * a33.w;

    float4* la = (float4*)lds_acc[wave];
    la[lane] = acc0; la[64 + lane] = acc1; la[128 + lane] = acc2; la[192 + lane] = acc3;
    __syncthreads();

    float Zg = lds_wz[0] + lds_wz[1] + lds_wz[2] + lds_wz[3]
             + lds_wz[4] + lds_wz[5] + lds_wz[6] + lds_wz[7];
    float inv = (Zg > 0.f) ? 1.0f / Zg : 0.f;

    // 8-way combine: thread t owns columns 2t, 2t+1
    float sx = 0.f, sy = 0.f;
    #pragma unroll
    for (int wv = 0; wv < 8; ++wv) {
        float2 v = *(const float2*)&lds_acc[wv][2 * tid];
        sx += v.x; sy += v.y;
    }
    float2 o = make_float2(sx * inv, sy * inv);
    *(float2*)&out[(long long)bn * OUTD + 2 * tid] = o;
}

extern "C" void kernel_launch(void* const* d_in, const int* in_sizes, int n_in,
                              void* d_out, int out_size, void* d_ws, size_t ws_size,
                              hipStream_t stream) {
    const float* seq  = (const float*)d_in[0];
    const int*   idx  = (const int*)d_in[1];
    const float* w    = (const float*)d_in[2];
    const float* wemb = (const float*)d_in[4];
    float* out = (float*)d_out;

    int4* meta = (int4*)d_ws;            // NSPAN * 16 B = 128 KB

    sort_kernel<<<1, 1024, 0, stream>>>((const int2*)idx, meta);
    span_kernel<<<NSPAN, 512, 0, stream>>>(seq, w, wemb, meta, out);
}

// Round 11
// 60.414 us; speedup vs baseline: 1.1474x; 1.0707x over previous
//
#include <hip/hip_runtime.h>

#define BB 8
#define SS 4096
#define NN 1024
#define DD 1024
#define NUM_WIDTH 64
#define WIDTH_DIM 64
#define OUTD (DD + WIDTH_DIM)   // 1088
#define NSPAN (BB * NN)         // 8192
#define NBUCK 128               // per-batch start buckets (start >> 5)
#define NBINS (BB * NBUCK)      // 1024

// ---- fused counting sort; emits sorted metadata records (bn,start,end) ----
__global__ __launch_bounds__(1024) void sort_kernel(const int2* __restrict__ idx2,
                                                    int4* __restrict__ meta) {
    __shared__ int cnt[NBINS];
    __shared__ int wsum[16];
    int tid = threadIdx.x, lane = tid & 63, wid = tid >> 6;
    cnt[tid] = 0;
    __syncthreads();

    for (int i = tid; i < NSPAN; i += 1024) {
        int2 se = idx2[i];
        int s0 = se.x > 0 ? se.x : 0;
        if (s0 > SS - 1) s0 = SS - 1;
        atomicAdd(&cnt[(i >> 10) * NBUCK + (s0 >> 5)], 1);
    }
    __syncthreads();

    // wave-level inclusive scan of the 1024 bin counts
    int orig = cnt[tid];
    int x = orig;
    #pragma unroll
    for (int d = 1; d < 64; d <<= 1) {
        int y = __shfl_up(x, d, 64);
        if (lane >= d) x += y;
    }
    if (lane == 63) wsum[wid] = x;
    __syncthreads();
    if (wid == 0) {
        int s = (lane < 16) ? wsum[lane] : 0;
        #pragma unroll
        for (int d = 1; d < 16; d <<= 1) {
            int y = __shfl_up(s, d, 64);
            if (lane >= d) s += y;
        }
        if (lane < 16) wsum[lane] = s;
    }
    __syncthreads();
    int excl = x - orig + (wid > 0 ? wsum[wid - 1] : 0);
    __syncthreads();
    cnt[tid] = excl;
    __syncthreads();

    for (int i = tid; i < NSPAN; i += 1024) {
        int2 se = idx2[i];
        int s0 = se.x > 0 ? se.x : 0;
        if (s0 > SS - 1) s0 = SS - 1;
        int pos = atomicAdd(&cnt[(i >> 10) * NBUCK + (s0 >> 5)], 1);
        meta[pos] = make_int4(i, se.x, se.y, 0);
    }
}

// ---- span kernel: ONE WAVE per span, 4-row batches, no LDS, no barriers ----
__global__ __launch_bounds__(256) void span_kernel(const float* __restrict__ seq,
                                                   const float* __restrict__ w,
                                                   const float* __restrict__ wemb,
                                                   const int4* __restrict__ meta,
                                                   float* __restrict__ out) {
    int wave = threadIdx.x >> 6;
    int lane = threadIdx.x & 63;
    // 4 consecutive sorted spans per block; XCD k gets a contiguous chunk.
    int slot = ((blockIdx.x & 7) * (NSPAN / 32) + (blockIdx.x >> 3)) * 4 + wave;
    int4 me = meta[slot];
    int bn = me.x, start = me.y, end = me.z;
    int b  = bn >> 10;

    int s0 = start > 0 ? start : 0;
    int eC = end < (SS - 1) ? end : (SS - 1);
    int L  = (start >= 0 && end >= start) ? (eC - s0 + 1) : 0;
    if (L < 0) L = 0;
    if (L > 32) L = 32;

    // width embedding: 64 lanes, one float each (independent store)
    {
        int wdt = end - start;
        if (wdt < 0) wdt = 0;
        if (wdt > NUM_WIDTH - 1) wdt = NUM_WIDTH - 1;
        out[(long long)bn * OUTD + DD + lane] = wemb[wdt * WIDTH_DIM + lane];
    }

    const float4* s4 = (const float4*)(seq + ((long long)b * SS + s0) * DD);
    const float4* w4 = (const float4*)w;
    float4 wr0 = w4[lane], wr1 = w4[64 + lane], wr2 = w4[128 + lane], wr3 = w4[192 + lane];

    float m = -INFINITY, Z = 0.f;
    float4 acc0 = make_float4(0.f, 0.f, 0.f, 0.f);
    float4 acc1 = acc0, acc2 = acc0, acc3 = acc0;

    for (int rb = 0; rb < L; rb += 4) {
        bool v0 = true;               // rb < L by loop condition
        bool v1 = rb + 1 < L;
        bool v2 = rb + 2 < L;
        bool v3 = rb + 3 < L;

        float4 zz = make_float4(0.f, 0.f, 0.f, 0.f);
        float4 a00 = zz, a01 = zz, a02 = zz, a03 = zz;
        float4 a10 = zz, a11 = zz, a12 = zz, a13 = zz;
        float4 a20 = zz, a21 = zz, a22 = zz, a23 = zz;
        float4 a30 = zz, a31 = zz, a32 = zz, a33 = zz;

        const float4* p = s4 + (long long)rb * (DD / 4);
        { a00 = p[lane]; a01 = p[64 + lane]; a02 = p[128 + lane]; a03 = p[192 + lane]; }
        if (v1) { const float4* q = p + 1 * (DD / 4); a10 = q[lane]; a11 = q[64 + lane]; a12 = q[128 + lane]; a13 = q[192 + lane]; }
        if (v2) { const float4* q = p + 2 * (DD / 4); a20 = q[lane]; a21 = q[64 + lane]; a22 = q[128 + lane]; a23 = q[192 + lane]; }
        if (v3) { const float4* q = p + 3 * (DD / 4); a30 = q[lane]; a31 = q[64 + lane]; a32 = q[128 + lane]; a33 = q[192 + lane]; }

        float d0 = a00.x * wr0.x + a00.y * wr0.y + a00.z * wr0.z + a00.w * wr0.w
                 + a01.x * wr1.x + a01.y * wr1.y + a01.z * wr1.z + a01.w * wr1.w
                 + a02.x * wr2.x + a02.y * wr2.y + a02.z * wr2.z + a02.w * wr2.w
                 + a03.x * wr3.x + a03.y * wr3.y + a03.z * wr3.z + a03.w * wr3.w;
        float d1 = a10.x * wr0.x + a10.y * wr0.y + a10.z * wr0.z + a10.w * wr0.w
                 + a11.x * wr1.x + a11.y * wr1.y + a11.z * wr1.z + a11.w * wr1.w
                 + a12.x * wr2.x + a12.y * wr2.y + a12.z * wr2.z + a12.w * wr2.w
                 + a13.x * wr3.x + a13.y * wr3.y + a13.z * wr3.z + a13.w * wr3.w;
        float d2 = a20.x * wr0.x + a20.y * wr0.y + a20.z * wr0.z + a20.w * wr0.w
                 + a21.x * wr1.x + a21.y * wr1.y + a21.z * wr1.z + a21.w * wr1.w
                 + a22.x * wr2.x + a22.y * wr2.y + a22.z * wr2.z + a22.w * wr2.w
                 + a23.x * wr3.x + a23.y * wr3.y + a23.z * wr3.z + a23.w * wr3.w;
        float d3 = a30.x * wr0.x + a30.y * wr0.y + a30.z * wr0.z + a30.w * wr0.w
                 + a31.x * wr1.x + a31.y * wr1.y + a31.z * wr1.z + a31.w * wr1.w
                 + a32.x * wr2.x + a32.y * wr2.y + a32.z * wr2.z + a32.w * wr2.w
                 + a33.x * wr3.x + a33.y * wr3.y + a33.z * wr3.z + a33.w * wr3.w;

        #pragma unroll
        for (int s = 32; s >= 1; s >>= 1) {
            d0 += __shfl_xor(d0, s, 64);
            d1 += __shfl_xor(d1, s, 64);
            d2 += __shfl_xor(d2, s, 64);
            d3 += __shfl_xor(d3, s, 64);
        }

        float dm = d0;
        if (v1) dm = fmaxf(dm, d1);
        if (v2) dm = fmaxf(dm, d2);
        if (v3) dm = fmaxf(dm, d3);

        if (dm > m) {                        // wave-uniform branch
            float f = __expf(m - dm);        // m==-inf -> f=0, zeroes stale state
            Z *= f;
            acc0.x *= f; acc0.y *= f; acc0.z *= f; acc0.w *= f;
            acc1.x *= f; acc1.y *= f; acc1.z *= f; acc1.w *= f;
            acc2.x *= f; acc2.y *= f; acc2.z *= f; acc2.w *= f;
            acc3.x *= f; acc3.y *= f; acc3.z *= f; acc3.w *= f;
            m = dm;
        }

        float x0 =      __expf(d0 - m);
        float x1 = v1 ? __expf(d1 - m) : 0.f;
        float x2 = v2 ? __expf(d2 - m) : 0.f;
        float x3 = v3 ? __expf(d3 - m) : 0.f;
        Z += x0 + x1 + x2 + x3;

        acc0.x += x0 * a00.x + x1 * a10.x + x2 * a20.x + x3 * a30.x;
        acc0.y += x0 * a00.y + x1 * a10.y + x2 * a20.y + x3 * a30.y;
        acc0.z += x0 * a00.z + x1 * a10.z + x2 * a20.z + x3 * a30.z;
        acc0.w += x0 * a00.w + x1 * a10.w + x2 * a20.w + x3 * a30.w;
        acc1.x += x0 * a01.x + x1 * a11.x + x2 * a21.x + x3 * a31.x;
        acc1.y += x0 * a01.y + x1 * a11.y + x2 * a21.y + x3 * a31.y;
        acc1.z += x0 * a01.z + x1 * a11.z + x2 * a21.z + x3 * a31.z;
        acc1.w += x0 * a01.w + x1 * a11.w + x2 * a21.w + x3 * a31.w;
        acc2.x += x0 * a02.x + x1 * a12.x + x2 * a22.x + x3 * a32.x;
        acc2.y += x0 * a02.y + x1 * a12.y + x2 * a22.y + x3 * a32.y;
        acc2.z += x0 * a02.z + x1 * a12.z + x2 * a22.z + x3 * a32.z;
        acc2.w += x0 * a02.w + x1 * a12.w + x2 * a22.w + x3 * a32.w;
        acc3.x += x0 * a03.x + x1 * a13.x + x2 * a23.x + x3 * a33.x;
        acc3.y += x0 * a03.y + x1 * a13.y + x2 * a23.y + x3 * a33.y;
        acc3.z += x0 * a03.z + x1 * a13.z + x2 * a23.z + x3 * a33.z;
        acc3.w += x0 * a03.w + x1 * a13.w + x2 * a23.w + x3 * a33.w;
    }

    float inv = (Z > 0.f) ? 1.0f / Z : 0.f;
    float4* o4 = (float4*)(out + (long long)bn * OUTD);
    float4 o;
    o.x = acc0.x * inv; o.y = acc0.y * inv; o.z = acc0.z * inv; o.w = acc0.w * inv;
    o4[lane] = o;
    o.x = acc1.x * inv; o.y = acc1.y * inv; o.z = acc1.z * inv; o.w = acc1.w * inv;
    o4[64 + lane] = o;
    o.x = acc2.x * inv; o.y = acc2.y * inv; o.z = acc2.z * inv; o.w = acc2.w * inv;
    o4[128 + lane] = o;
    o.x = acc3.x * inv; o.y = acc3.y * inv; o.z = acc3.z * inv; o.w = acc3.w * inv;
    o4[192 + lane] = o;
}

extern "C" void kernel_launch(void* const* d_in, const int* in_sizes, int n_in,
                              void* d_out, int out_size, void* d_ws, size_t ws_size,
                              hipStream_t stream) {
    const float* seq  = (const float*)d_in[0];
    const int*   idx  = (const int*)d_in[1];
    const float* w    = (const float*)d_in[2];
    const float* wemb = (const float*)d_in[4];
    float* out = (float*)d_out;

    int4* meta = (int4*)d_ws;            // NSPAN * 16 B = 128 KB

    sort_kernel<<<1, 1024, 0, stream>>>((const int2*)idx, meta);
    span_kernel<<<NSPAN / 4, 256, 0, stream>>>(seq, w, wemb, meta, out);
}